// Round 8
// baseline (154.824 us; speedup 1.0000x reference)
//
#include <hip/hip_runtime.h>
#include <math.h>

#define NATOM 300000
#define NBOND 310000
#define NANGLE 550000
#define NTORSION 800000
#define N14 800000
#define NNB 3000000
#define NTILE 18750   // NATOM/16

// output segment offsets (concat order from reference)
#define OFF_KATOM   0
#define OFF_EQATOM  300000
#define OFF_BOND0   600000
#define OFF_BOND1   910000
#define OFF_ANG0    1220000
#define OFF_ANG1    1770000
#define OFF_TOR0    2320000
#define OFF_TOR1    3120000
#define OFF_S14     3920000
#define OFF_E14     4720000
#define OFF_SNB     5520000
#define OFF_ENB     8520000

// tail kernel work-block counts (2 lanes per edge row)
#define NB_TOR2  6250   // 2*800000/256 exact
#define NB_ANG2  4297   // ceil(2*550000/256)
#define NB_BOND2 2422   // ceil(2*310000/256)
#define NB_14    1563   // ceil(400000/256), 2 pairs/thread
#define NB_NB    5860   // ceil(1500000/256), 2 pairs/thread
// interleaved mapping: groups of 11 blocks = 7 edge-stream + 4 pair-stream
// (edge total 12969, pair total 7423; ratio ~1.75)
#define E_TOT   (NB_TOR2 + NB_ANG2 + NB_BOND2)   // 12969
#define P_TOT   (NB_14 + NB_NB)                  // 7423
#define GROUPS  1856                             // ceil(E/7)=1853, ceil(P/4)=1856
#define NB_TAIL (GROUPS * 11)

// workspace: [frag table 16KB][zb bf16 19.2MB][ke float2 2.4MB]
#define FRAG_BYTES  16384
#define ZB_BYTES    ((size_t)NATOM * 32 * 2)
#define KE_OFF      (FRAG_BYTES + ZB_BYTES)
#define WS_NEED     (KE_OFF + (size_t)NATOM * 8)

typedef short bf16x8 __attribute__((ext_vector_type(8)));
typedef float f32x4  __attribute__((ext_vector_type(4)));

__device__ __forceinline__ float fast_tanh(float z) {
    float az = fabsf(z);
    float e  = __expf(-2.0f * az);
    float t  = __fdividef(1.0f - e, 1.0f + e);
    return copysignf(t, z);
}

__device__ __forceinline__ unsigned short f2bf(float f) {
    unsigned int u = __float_as_uint(f);
    u = u + 0x7fffu + ((u >> 16) & 1u);   // RTNE
    return (unsigned short)(u >> 16);
}

// ---------------- fast path ----------------

// Pre-pack B fragments of W1a/W1b for mfma_f32_16x16x32_bf16 (r3 verbatim).
__global__ __launch_bounds__(256)
void build_frags_k(const float* __restrict__ W1a, const float* __restrict__ W1b,
                   ushort* __restrict__ frag)
{
    int s = blockIdx.x * 256 + threadIdx.x;   // 1024 slots
    if (s >= 1024) return;
    int lane = s & 63;
    int f    = s >> 6;
    int cb   = f & 1;
    int t    = (f >> 1) & 3;
    int mat  = f >> 3;
    const float* W = mat ? W1b : W1a;
    int k0  = t * 32 + (lane >> 4) * 8;
    int col = cb * 16 + (lane & 15);
    ushort* dst = frag + (size_t)s * 8;
    #pragma unroll
    for (int i = 0; i < 8; ++i)
        dst[i] = f2bf(W[(size_t)(k0 + i) * 32 + col]);
}

// r3/r6 verbatim: one 16-row tile per wave, 4 waves/block, direct z stores.
__global__ __launch_bounds__(256)
void atom_mfma_k(const float* __restrict__ h, const bf16x8* __restrict__ frag,
                 const float* __restrict__ b1a, const float* __restrict__ W2a,
                 const float* __restrict__ b2a,
                 float* __restrict__ kout, float* __restrict__ eout,
                 ushort* __restrict__ zb, float2* __restrict__ ke)
{
    const int wid  = threadIdx.x >> 6;
    const int lane = threadIdx.x & 63;
    const int tile = blockIdx.x * 4 + wid;
    if (tile >= NTILE) return;
    const int rowbase = tile * 16;
    const int m = lane & 15;
    const int g = lane >> 4;

    const float* ap = h + (size_t)(rowbase + m) * 128 + g * 8;
    bf16x8 afr[4];
    #pragma unroll
    for (int t = 0; t < 4; ++t) {
        float4 x0 = *(const float4*)(ap + t * 32);
        float4 x1 = *(const float4*)(ap + t * 32 + 4);
        bf16x8 a;
        a[0] = (short)f2bf(x0.x); a[1] = (short)f2bf(x0.y);
        a[2] = (short)f2bf(x0.z); a[3] = (short)f2bf(x0.w);
        a[4] = (short)f2bf(x1.x); a[5] = (short)f2bf(x1.y);
        a[6] = (short)f2bf(x1.z); a[7] = (short)f2bf(x1.w);
        afr[t] = a;
    }

    f32x4 acc[2][2];
    #pragma unroll
    for (int mat = 0; mat < 2; ++mat) {
        #pragma unroll
        for (int cb = 0; cb < 2; ++cb) {
            f32x4 c = {0.f, 0.f, 0.f, 0.f};
            #pragma unroll
            for (int t = 0; t < 4; ++t) {
                bf16x8 b = frag[(size_t)((((mat << 2) | t) << 1) | cb) * 64 + lane];
                c = __builtin_amdgcn_mfma_f32_16x16x32_bf16(afr[t], b, c, 0, 0, 0);
            }
            acc[mat][cb] = c;
        }
    }

    // z output (mat=1), bf16, direct scattered stores
    #pragma unroll
    for (int cb = 0; cb < 2; ++cb) {
        int col = cb * 16 + m;
        #pragma unroll
        for (int r = 0; r < 4; ++r) {
            int row = rowbase + g * 4 + r;
            zb[(size_t)row * 32 + col] = f2bf(acc[1][cb][r]);
        }
    }

    // atom MLP epilogue (mat=0)
    const int c0 = m, c1 = 16 + m;
    const float w200 = W2a[2 * c0], w201 = W2a[2 * c0 + 1];
    const float w210 = W2a[2 * c1], w211 = W2a[2 * c1 + 1];
    const float bb0 = b1a[c0], bb1 = b1a[c1];
    float o0[4], o1[4];
    #pragma unroll
    for (int r = 0; r < 4; ++r) {
        float t0 = fast_tanh(acc[0][0][r] + bb0);
        float t1 = fast_tanh(acc[0][1][r] + bb1);
        o0[r] = fmaf(t0, w200, t1 * w210);
        o1[r] = fmaf(t0, w201, t1 * w211);
    }
    #pragma unroll
    for (int mask = 1; mask < 16; mask <<= 1) {
        #pragma unroll
        for (int r = 0; r < 4; ++r) {
            o0[r] += __shfl_xor(o0[r], mask, 64);
            o1[r] += __shfl_xor(o1[r], mask, 64);
        }
    }
    if (m == 0) {
        const float B0 = b2a[0], B1 = b2a[1];
        #pragma unroll
        for (int r = 0; r < 4; ++r) {
            int row = rowbase + g * 4 + r;
            float kv = fabsf(o0[r] + B0);
            float ev = fabsf(o1[r] + B1);
            kout[row] = kv;
            eout[row] = ev;
            ke[row]   = make_float2(kv, ev);
        }
    }
}

// Half-row edge body (r7 verbatim): lane pair (2r,2r+1) splits one edge row's
// 32 hidden units; each lane gathers 32B (2x uint4) per source row.
template<int MODE>
__device__ __forceinline__ void edge_half_body(const ushort* __restrict__ zb,
                                               const int* __restrict__ ia,
                                               const int* __restrict__ ib,
                                               const float* __restrict__ b1,
                                               const float* __restrict__ W2,
                                               const float* __restrict__ b2,
                                               float* __restrict__ o0p,
                                               float* __restrict__ o1p,
                                               int row, int half)
{
    const uint4* p0;
    const uint4* p1;
    const uint4* p2 = nullptr;
    if constexpr (MODE == 1) {
        int2 p = ((const int2*)ia)[row];
        p0 = (const uint4*)(zb + (size_t)p.x * 32) + half * 2;
        p1 = (const uint4*)(zb + (size_t)p.y * 32) + half * 2;
    } else if constexpr (MODE == 2) {
        int c  = ia[row];
        int2 s = ((const int2*)ib)[row];
        p0 = (const uint4*)(zb + (size_t)c   * 32) + half * 2;
        p1 = (const uint4*)(zb + (size_t)s.x * 32) + half * 2;
        p2 = (const uint4*)(zb + (size_t)s.y * 32) + half * 2;
    } else {
        int4 q = ((const int4*)ia)[row];
        p0 = (const uint4*)(zb + (size_t)q.z * 32) + half * 2;
        p1 = (const uint4*)(zb + (size_t)q.w * 32) + half * 2;
    }

    // all gathers issued before any unpack/compute
    uint4 r0[2], r1[2], r2[2];
    r0[0] = p0[0]; r0[1] = p0[1];
    r1[0] = p1[0]; r1[1] = p1[1];
    if constexpr (MODE == 2) { r2[0] = p2[0]; r2[1] = p2[1]; }

    const int jb = half * 16;
    float acc[16];
    #pragma unroll
    for (int c = 0; c < 2; ++c) {
        unsigned int w0[4] = {r0[c].x, r0[c].y, r0[c].z, r0[c].w};
        unsigned int w1[4] = {r1[c].x, r1[c].y, r1[c].z, r1[c].w};
        #pragma unroll
        for (int q = 0; q < 4; ++q) {
            float s0 = __uint_as_float(w0[q] << 16)         + __uint_as_float(w1[q] << 16);
            float s1 = __uint_as_float(w0[q] & 0xffff0000u) + __uint_as_float(w1[q] & 0xffff0000u);
            if constexpr (MODE == 2) {
                unsigned int w2v = (q == 0) ? r2[c].x : (q == 1) ? r2[c].y
                                 : (q == 2) ? r2[c].z : r2[c].w;
                s0 += __uint_as_float(w2v << 16);
                s1 += __uint_as_float(w2v & 0xffff0000u);
            }
            acc[c * 8 + q * 2]     = s0 + b1[jb + c * 8 + q * 2];
            acc[c * 8 + q * 2 + 1] = s1 + b1[jb + c * 8 + q * 2 + 1];
        }
    }

    float o0 = 0.0f, o1 = 0.0f;
    #pragma unroll
    for (int j = 0; j < 16; ++j) {
        float t = fast_tanh(acc[j]);
        o0 = fmaf(t, W2[2 * (jb + j)],     o0);
        o1 = fmaf(t, W2[2 * (jb + j) + 1], o1);
    }
    o0 += __shfl_xor(o0, 1, 64);
    o1 += __shfl_xor(o1, 1, 64);
    if (half == 0) {
        o0p[row] = fabsf(o0 + b2[0]);
        o1p[row] = fabsf(o1 + b2[1]);
    }
}

__device__ __forceinline__ void pair_body(const float2* __restrict__ ke,
                                          const int* __restrict__ idx,
                                          float* __restrict__ sig,
                                          float* __restrict__ eps,
                                          int i, int npair)
{
    if (i >= npair) return;
    int4 q = ((const int4*)idx)[i >> 1];
    float2 a0 = ke[q.x], b0 = ke[q.y];
    float2 a1 = ke[q.z], b1v = ke[q.w];
    sig[i]     = 0.5f * (a0.x + b0.x);
    eps[i]     = sqrtf(a0.y * b0.y);
    sig[i + 1] = 0.5f * (a1.x + b1v.x);
    eps[i + 1] = sqrtf(a1.y * b1v.y);
}

// All edge MLPs (2 lanes/row) + both pair readouts in ONE dispatch.
// Blocks are STRIPED 7 edge : 4 pair per group of 11, so the L2-resident
// pair phase executes in the latency shadows of the L2-miss-bound edge
// gathers instead of serially after them.
__global__ __launch_bounds__(256)
void tail_k(const ushort* __restrict__ zb, const float2* __restrict__ ke,
            const int* __restrict__ bond, const int* __restrict__ angc,
            const int* __restrict__ angs, const int* __restrict__ tor,
            const int* __restrict__ i14, const int* __restrict__ inb,
            const float* __restrict__ b1, const float* __restrict__ W2,
            const float* __restrict__ b2, float* __restrict__ out)
{
    int bid = blockIdx.x;
    int tid = threadIdx.x;
    int g = bid / 11;
    int r = bid % 11;
    if (r < 7) {
        int eb = g * 7 + r;
        if (eb >= E_TOT) return;
        if (eb < NB_TOR2) {
            int t2 = eb * 256 + tid;           // < 2*NTORSION exact
            edge_half_body<3>(zb, tor, nullptr, b1, W2, b2,
                              out + OFF_TOR0, out + OFF_TOR1, t2 >> 1, t2 & 1);
        } else if (eb < NB_TOR2 + NB_ANG2) {
            int t2 = (eb - NB_TOR2) * 256 + tid;
            if (t2 < 2 * NANGLE)
                edge_half_body<2>(zb, angc, angs, b1, W2, b2,
                                  out + OFF_ANG0, out + OFF_ANG1, t2 >> 1, t2 & 1);
        } else {
            int t2 = (eb - NB_TOR2 - NB_ANG2) * 256 + tid;
            if (t2 < 2 * NBOND)
                edge_half_body<1>(zb, bond, nullptr, b1, W2, b2,
                                  out + OFF_BOND0, out + OFF_BOND1, t2 >> 1, t2 & 1);
        }
    } else {
        int pb = g * 4 + (r - 7);
        if (pb >= P_TOT) return;
        if (pb < NB_14) {
            int i = (pb * 256 + tid) * 2;
            pair_body(ke, i14, out + OFF_S14, out + OFF_E14, i, N14);
        } else {
            int i = ((pb - NB_14) * 256 + tid) * 2;
            pair_body(ke, inb, out + OFF_SNB, out + OFF_ENB, i, NNB);
        }
    }
}

// ---------------- fallback path (v1, known-good) ----------------

template<int MODE>
__global__ __launch_bounds__(256)
void mlp_k(const float* __restrict__ h,
           const int* __restrict__ ia, const int* __restrict__ ib,
           const float* __restrict__ W1, const float* __restrict__ b1,
           const float* __restrict__ W2, const float* __restrict__ b2,
           float* __restrict__ o0p, float* __restrict__ o1p, int n)
{
    __shared__ float sW1[128 * 32];
    __shared__ float sB1[32];
    __shared__ float sW2[64];
    __shared__ float sB2[2];

    const int tid = threadIdx.x;
    {
        const float4* W1v = (const float4*)W1;
        float4* sW1v = (float4*)sW1;
        #pragma unroll
        for (int i = 0; i < 4; ++i) sW1v[tid + 256 * i] = W1v[tid + 256 * i];
        if (tid < 32) sB1[tid] = b1[tid];
        if (tid < 64) sW2[tid] = W2[tid];
        if (tid < 2)  sB2[tid] = b2[tid];
    }
    __syncthreads();

    const int row = blockIdx.x * 256 + tid;
    if (row >= n) return;

    const float4* x0;
    const float4* x1 = nullptr;
    const float4* x2 = nullptr;
    if constexpr (MODE == 0) {
        x0 = (const float4*)(h + (size_t)row * 128);
    } else if constexpr (MODE == 1) {
        int2 p = ((const int2*)ia)[row];
        x0 = (const float4*)(h + (size_t)p.x * 128);
        x1 = (const float4*)(h + (size_t)p.y * 128);
    } else if constexpr (MODE == 2) {
        int c  = ia[row];
        int2 p = ((const int2*)ib)[row];
        x0 = (const float4*)(h + (size_t)c * 128);
        x1 = (const float4*)(h + (size_t)p.x * 128);
        x2 = (const float4*)(h + (size_t)p.y * 128);
    } else {
        int4 q = ((const int4*)ia)[row];
        x0 = (const float4*)(h + (size_t)q.z * 128);
        x1 = (const float4*)(h + (size_t)q.w * 128);
    }

    float acc[32];
    #pragma unroll
    for (int j = 0; j < 32; ++j) acc[j] = sB1[j];

    #pragma unroll 2
    for (int kk = 0; kk < 32; ++kk) {
        float4 a = x0[kk];
        if constexpr (MODE == 1 || MODE == 3) {
            float4 bq = x1[kk];
            a.x += bq.x; a.y += bq.y; a.z += bq.z; a.w += bq.w;
        } else if constexpr (MODE == 2) {
            float4 bq = x1[kk];
            float4 cq = x2[kk];
            a.x += bq.x + cq.x; a.y += bq.y + cq.y;
            a.z += bq.z + cq.z; a.w += bq.w + cq.w;
        }
        const float* wr = &sW1[kk * 4 * 32];
        #pragma unroll
        for (int j = 0; j < 32; ++j) acc[j] = fmaf(a.x, wr[j], acc[j]);
        #pragma unroll
        for (int j = 0; j < 32; ++j) acc[j] = fmaf(a.y, wr[32 + j], acc[j]);
        #pragma unroll
        for (int j = 0; j < 32; ++j) acc[j] = fmaf(a.z, wr[64 + j], acc[j]);
        #pragma unroll
        for (int j = 0; j < 32; ++j) acc[j] = fmaf(a.w, wr[96 + j], acc[j]);
    }

    float o0 = sB2[0], o1 = sB2[1];
    #pragma unroll
    for (int j = 0; j < 32; ++j) {
        float t = fast_tanh(acc[j]);
        o0 = fmaf(t, sW2[2 * j], o0);
        o1 = fmaf(t, sW2[2 * j + 1], o1);
    }
    o0p[row] = fabsf(o0);
    o1p[row] = fabsf(o1);
}

__global__ __launch_bounds__(256)
void pair_k(const float* __restrict__ kat, const float* __restrict__ eat,
            const int* __restrict__ idx,
            float* __restrict__ sig, float* __restrict__ eps, int n)
{
    int i = blockIdx.x * 256 + threadIdx.x;
    if (i >= n) return;
    int2 p = ((const int2*)idx)[i];
    float ka = kat[p.x], kb = kat[p.y];
    float ea = eat[p.x], eb = eat[p.y];
    sig[i] = 0.5f * (ka + kb);
    eps[i] = sqrtf(ea * eb);
}

extern "C" void kernel_launch(void* const* d_in, const int* in_sizes, int n_in,
                              void* d_out, int out_size, void* d_ws, size_t ws_size,
                              hipStream_t stream)
{
    const float* h     = (const float*)d_in[0];
    const int*   bond  = (const int*)d_in[1];
    const int*   ang_c = (const int*)d_in[2];
    const int*   ang_s = (const int*)d_in[3];
    const int*   tor   = (const int*)d_in[4];
    const int*   i14   = (const int*)d_in[5];
    const int*   inb   = (const int*)d_in[6];
    const float* W1a   = (const float*)d_in[7];
    const float* b1a   = (const float*)d_in[8];
    const float* W2a   = (const float*)d_in[9];
    const float* b2a   = (const float*)d_in[10];
    const float* W1b   = (const float*)d_in[11];
    const float* b1b   = (const float*)d_in[12];
    const float* W2b   = (const float*)d_in[13];
    const float* b2b   = (const float*)d_in[14];
    float* out = (float*)d_out;

    dim3 B(256);

    if (ws_size >= WS_NEED) {
        ushort* fragS = (ushort*)d_ws;
        const bf16x8* fragV = (const bf16x8*)d_ws;
        ushort* zb = (ushort*)((char*)d_ws + FRAG_BYTES);
        float2* ke = (float2*)((char*)d_ws + KE_OFF);

        build_frags_k<<<4, B, 0, stream>>>(W1a, W1b, fragS);

        atom_mfma_k<<<(NTILE + 3) / 4, B, 0, stream>>>(
            h, fragV, b1a, W2a, b2a,
            out + OFF_KATOM, out + OFF_EQATOM, zb, ke);

        tail_k<<<NB_TAIL, B, 0, stream>>>(
            zb, ke, bond, ang_c, ang_s, tor, i14, inb,
            b1b, W2b, b2b, out);
    } else {
        mlp_k<0><<<(NATOM    + 255) / 256, B, 0, stream>>>(h, nullptr, nullptr, W1a, b1a, W2a, b2a,
                                                           out + OFF_KATOM, out + OFF_EQATOM, NATOM);
        mlp_k<1><<<(NBOND    + 255) / 256, B, 0, stream>>>(h, bond, nullptr, W1b, b1b, W2b, b2b,
                                                           out + OFF_BOND0, out + OFF_BOND1, NBOND);
        mlp_k<2><<<(NANGLE   + 255) / 256, B, 0, stream>>>(h, ang_c, ang_s, W1b, b1b, W2b, b2b,
                                                           out + OFF_ANG0, out + OFF_ANG1, NANGLE);
        mlp_k<3><<<(NTORSION + 255) / 256, B, 0, stream>>>(h, tor, nullptr, W1b, b1b, W2b, b2b,
                                                           out + OFF_TOR0, out + OFF_TOR1, NTORSION);
        pair_k<<<(N14 + 255) / 256, B, 0, stream>>>(out + OFF_KATOM, out + OFF_EQATOM, i14,
                                                    out + OFF_S14, out + OFF_E14, N14);
        pair_k<<<(NNB + 255) / 256, B, 0, stream>>>(out + OFF_KATOM, out + OFF_EQATOM, inb,
                                                    out + OFF_SNB, out + OFF_ENB, NNB);
    }
}

// Round 9
// 150.853 us; speedup vs baseline: 1.0263x; 1.0263x over previous
//
#include <hip/hip_runtime.h>
#include <math.h>

#define NATOM 300000
#define NBOND 310000
#define NANGLE 550000
#define NTORSION 800000
#define N14 800000
#define NNB 3000000
#define NTILE 18750   // NATOM/16

// output segment offsets (concat order from reference)
#define OFF_KATOM   0
#define OFF_EQATOM  300000
#define OFF_BOND0   600000
#define OFF_BOND1   910000
#define OFF_ANG0    1220000
#define OFF_ANG1    1770000
#define OFF_TOR0    2320000
#define OFF_TOR1    3120000
#define OFF_S14     3920000
#define OFF_E14     4720000
#define OFF_SNB     5520000
#define OFF_ENB     8520000

// tail kernel block ranges (r6 sequential layout — interleave regressed, r8)
#define NB_TOR   3125   // 800000/256 exact
#define NB_ANG   2149   // ceil(550000/256)
#define NB_BOND  1211   // ceil(310000/256)
#define NB_14    1563   // ceil(400000/256), 2 pairs/thread
#define NB_NB    5860   // ceil(1500000/256), 2 pairs/thread
#define NB_TAIL  (NB_TOR + NB_ANG + NB_BOND + NB_14 + NB_NB)

// workspace: [frag table 16KB][zb bf16 19.2MB][ke float2 2.4MB]
#define FRAG_BYTES  16384
#define ZB_BYTES    ((size_t)NATOM * 32 * 2)
#define KE_OFF      (FRAG_BYTES + ZB_BYTES)
#define WS_NEED     (KE_OFF + (size_t)NATOM * 8)

typedef short bf16x8 __attribute__((ext_vector_type(8)));
typedef float f32x4  __attribute__((ext_vector_type(4)));
typedef float f32x4v __attribute__((ext_vector_type(4)));
typedef int   i32x2v __attribute__((ext_vector_type(2)));
typedef int   i32x4v __attribute__((ext_vector_type(4)));

// nontemporal hints: stream read-once/write-once data through L2 without
// allocating, preserving L2 capacity for the random zb/ke gathers.
#if __has_builtin(__builtin_nontemporal_load)
#define NT_LOAD(p)     __builtin_nontemporal_load(p)
#else
#define NT_LOAD(p)     (*(p))
#endif
#if __has_builtin(__builtin_nontemporal_store)
#define NT_STORE(v, p) __builtin_nontemporal_store((v), (p))
#else
#define NT_STORE(v, p) (*(p) = (v))
#endif

__device__ __forceinline__ float fast_tanh(float z) {
    float az = fabsf(z);
    float e  = __expf(-2.0f * az);
    float t  = __fdividef(1.0f - e, 1.0f + e);
    return copysignf(t, z);
}

__device__ __forceinline__ unsigned short f2bf(float f) {
    unsigned int u = __float_as_uint(f);
    u = u + 0x7fffu + ((u >> 16) & 1u);   // RTNE
    return (unsigned short)(u >> 16);
}

// ---------------- fast path ----------------

// Pre-pack B fragments of W1a/W1b for mfma_f32_16x16x32_bf16 (r3 verbatim).
__global__ __launch_bounds__(256)
void build_frags_k(const float* __restrict__ W1a, const float* __restrict__ W1b,
                   ushort* __restrict__ frag)
{
    int s = blockIdx.x * 256 + threadIdx.x;   // 1024 slots
    if (s >= 1024) return;
    int lane = s & 63;
    int f    = s >> 6;
    int cb   = f & 1;
    int t    = (f >> 1) & 3;
    int mat  = f >> 3;
    const float* W = mat ? W1b : W1a;
    int k0  = t * 32 + (lane >> 4) * 8;
    int col = cb * 16 + (lane & 15);
    ushort* dst = frag + (size_t)s * 8;
    #pragma unroll
    for (int i = 0; i < 8; ++i)
        dst[i] = f2bf(W[(size_t)(k0 + i) * 32 + col]);
}

// r3/r6 structure: one 16-row tile per wave, 4 waves/block, direct z stores.
// h loads are nontemporal (read-once 153.6MB stream).
__global__ __launch_bounds__(256)
void atom_mfma_k(const float* __restrict__ h, const bf16x8* __restrict__ frag,
                 const float* __restrict__ b1a, const float* __restrict__ W2a,
                 const float* __restrict__ b2a,
                 float* __restrict__ kout, float* __restrict__ eout,
                 ushort* __restrict__ zb, float2* __restrict__ ke)
{
    const int wid  = threadIdx.x >> 6;
    const int lane = threadIdx.x & 63;
    const int tile = blockIdx.x * 4 + wid;
    if (tile >= NTILE) return;
    const int rowbase = tile * 16;
    const int m = lane & 15;
    const int g = lane >> 4;

    const float* ap = h + (size_t)(rowbase + m) * 128 + g * 8;
    bf16x8 afr[4];
    #pragma unroll
    for (int t = 0; t < 4; ++t) {
        f32x4v x0 = NT_LOAD((const f32x4v*)(ap + t * 32));
        f32x4v x1 = NT_LOAD((const f32x4v*)(ap + t * 32 + 4));
        bf16x8 a;
        a[0] = (short)f2bf(x0.x); a[1] = (short)f2bf(x0.y);
        a[2] = (short)f2bf(x0.z); a[3] = (short)f2bf(x0.w);
        a[4] = (short)f2bf(x1.x); a[5] = (short)f2bf(x1.y);
        a[6] = (short)f2bf(x1.z); a[7] = (short)f2bf(x1.w);
        afr[t] = a;
    }

    f32x4 acc[2][2];
    #pragma unroll
    for (int mat = 0; mat < 2; ++mat) {
        #pragma unroll
        for (int cb = 0; cb < 2; ++cb) {
            f32x4 c = {0.f, 0.f, 0.f, 0.f};
            #pragma unroll
            for (int t = 0; t < 4; ++t) {
                bf16x8 b = frag[(size_t)((((mat << 2) | t) << 1) | cb) * 64 + lane];
                c = __builtin_amdgcn_mfma_f32_16x16x32_bf16(afr[t], b, c, 0, 0, 0);
            }
            acc[mat][cb] = c;
        }
    }

    // z output (mat=1), bf16, direct scattered stores
    #pragma unroll
    for (int cb = 0; cb < 2; ++cb) {
        int col = cb * 16 + m;
        #pragma unroll
        for (int r = 0; r < 4; ++r) {
            int row = rowbase + g * 4 + r;
            zb[(size_t)row * 32 + col] = f2bf(acc[1][cb][r]);
        }
    }

    // atom MLP epilogue (mat=0)
    const int c0 = m, c1 = 16 + m;
    const float w200 = W2a[2 * c0], w201 = W2a[2 * c0 + 1];
    const float w210 = W2a[2 * c1], w211 = W2a[2 * c1 + 1];
    const float bb0 = b1a[c0], bb1 = b1a[c1];
    float o0[4], o1[4];
    #pragma unroll
    for (int r = 0; r < 4; ++r) {
        float t0 = fast_tanh(acc[0][0][r] + bb0);
        float t1 = fast_tanh(acc[0][1][r] + bb1);
        o0[r] = fmaf(t0, w200, t1 * w210);
        o1[r] = fmaf(t0, w201, t1 * w211);
    }
    #pragma unroll
    for (int mask = 1; mask < 16; mask <<= 1) {
        #pragma unroll
        for (int r = 0; r < 4; ++r) {
            o0[r] += __shfl_xor(o0[r], mask, 64);
            o1[r] += __shfl_xor(o1[r], mask, 64);
        }
    }
    if (m == 0) {
        const float B0 = b2a[0], B1 = b2a[1];
        #pragma unroll
        for (int r = 0; r < 4; ++r) {
            int row = rowbase + g * 4 + r;
            float kv = fabsf(o0[r] + B0);
            float ev = fabsf(o1[r] + B1);
            kout[row] = kv;
            eout[row] = ev;
            ke[row]   = make_float2(kv, ev);
        }
    }
}

__device__ __forceinline__ void add_row_bf(float* acc, const uint4* p) {
    #pragma unroll
    for (int c = 0; c < 4; ++c) {
        uint4 u = p[c];
        unsigned int w[4] = {u.x, u.y, u.z, u.w};
        #pragma unroll
        for (int q = 0; q < 4; ++q) {
            acc[c * 8 + q * 2]     += __uint_as_float(w[q] << 16);
            acc[c * 8 + q * 2 + 1] += __uint_as_float(w[q] & 0xffff0000u);
        }
    }
}

// r6 full-row edge body; index loads nontemporal, output stores nontemporal,
// zb gathers normal (cached — they are the reuse candidates).
template<int MODE>
__device__ __forceinline__ void edge_body(const ushort* __restrict__ zb,
                                          const int* __restrict__ ia,
                                          const int* __restrict__ ib,
                                          const float* __restrict__ b1,
                                          const float* __restrict__ W2,
                                          const float* __restrict__ b2,
                                          float* __restrict__ o0p,
                                          float* __restrict__ o1p, int row)
{
    const uint4* p0;
    const uint4* p1;
    const uint4* p2 = nullptr;
    if constexpr (MODE == 1) {
        i32x2v p = NT_LOAD((const i32x2v*)&((const int2*)ia)[row]);
        p0 = (const uint4*)(zb + (size_t)p.x * 32);
        p1 = (const uint4*)(zb + (size_t)p.y * 32);
    } else if constexpr (MODE == 2) {
        int c = NT_LOAD(&ia[row]);
        i32x2v s = NT_LOAD((const i32x2v*)&((const int2*)ib)[row]);
        p0 = (const uint4*)(zb + (size_t)c   * 32);
        p1 = (const uint4*)(zb + (size_t)s.x * 32);
        p2 = (const uint4*)(zb + (size_t)s.y * 32);
    } else {
        i32x4v q = NT_LOAD((const i32x4v*)&((const int4*)ia)[row]);
        p0 = (const uint4*)(zb + (size_t)q.z * 32);
        p1 = (const uint4*)(zb + (size_t)q.w * 32);
    }

    float acc[32];
    #pragma unroll
    for (int j = 0; j < 32; ++j) acc[j] = b1[j];
    add_row_bf(acc, p0);
    add_row_bf(acc, p1);
    if constexpr (MODE == 2) add_row_bf(acc, p2);

    float o0 = b2[0], o1 = b2[1];
    #pragma unroll
    for (int j = 0; j < 32; ++j) {
        float t = fast_tanh(acc[j]);
        o0 = fmaf(t, W2[2 * j],     o0);
        o1 = fmaf(t, W2[2 * j + 1], o1);
    }
    NT_STORE(fabsf(o0), &o0p[row]);
    NT_STORE(fabsf(o1), &o1p[row]);
}

__device__ __forceinline__ void pair_body(const float2* __restrict__ ke,
                                          const int* __restrict__ idx,
                                          float* __restrict__ sig,
                                          float* __restrict__ eps,
                                          int i, int npair)
{
    if (i >= npair) return;
    i32x4v q = NT_LOAD((const i32x4v*)&((const int4*)idx)[i >> 1]);
    float2 a0 = ke[q.x], b0 = ke[q.y];
    float2 a1 = ke[q.z], b1v = ke[q.w];
    NT_STORE(0.5f * (a0.x + b0.x),  &sig[i]);
    NT_STORE(sqrtf(a0.y * b0.y),    &eps[i]);
    NT_STORE(0.5f * (a1.x + b1v.x), &sig[i + 1]);
    NT_STORE(sqrtf(a1.y * b1v.y),   &eps[i + 1]);
}

// All edge MLPs + both pair readouts in ONE dispatch (r6 sequential routing).
__global__ __launch_bounds__(256)
void tail_k(const ushort* __restrict__ zb, const float2* __restrict__ ke,
            const int* __restrict__ bond, const int* __restrict__ angc,
            const int* __restrict__ angs, const int* __restrict__ tor,
            const int* __restrict__ i14, const int* __restrict__ inb,
            const float* __restrict__ b1, const float* __restrict__ W2,
            const float* __restrict__ b2, float* __restrict__ out)
{
    int bid = blockIdx.x;
    int tid = threadIdx.x;
    if (bid < NB_TOR) {
        int row = bid * 256 + tid;
        if (row < NTORSION)
            edge_body<3>(zb, tor, nullptr, b1, W2, b2,
                         out + OFF_TOR0, out + OFF_TOR1, row);
    } else if (bid < NB_TOR + NB_ANG) {
        int row = (bid - NB_TOR) * 256 + tid;
        if (row < NANGLE)
            edge_body<2>(zb, angc, angs, b1, W2, b2,
                         out + OFF_ANG0, out + OFF_ANG1, row);
    } else if (bid < NB_TOR + NB_ANG + NB_BOND) {
        int row = (bid - NB_TOR - NB_ANG) * 256 + tid;
        if (row < NBOND)
            edge_body<1>(zb, bond, nullptr, b1, W2, b2,
                         out + OFF_BOND0, out + OFF_BOND1, row);
    } else if (bid < NB_TOR + NB_ANG + NB_BOND + NB_14) {
        int i = ((bid - NB_TOR - NB_ANG - NB_BOND) * 256 + tid) * 2;
        pair_body(ke, i14, out + OFF_S14, out + OFF_E14, i, N14);
    } else {
        int i = ((bid - NB_TOR - NB_ANG - NB_BOND - NB_14) * 256 + tid) * 2;
        pair_body(ke, inb, out + OFF_SNB, out + OFF_ENB, i, NNB);
    }
}

// ---------------- fallback path (v1, known-good) ----------------

template<int MODE>
__global__ __launch_bounds__(256)
void mlp_k(const float* __restrict__ h,
           const int* __restrict__ ia, const int* __restrict__ ib,
           const float* __restrict__ W1, const float* __restrict__ b1,
           const float* __restrict__ W2, const float* __restrict__ b2,
           float* __restrict__ o0p, float* __restrict__ o1p, int n)
{
    __shared__ float sW1[128 * 32];
    __shared__ float sB1[32];
    __shared__ float sW2[64];
    __shared__ float sB2[2];

    const int tid = threadIdx.x;
    {
        const float4* W1v = (const float4*)W1;
        float4* sW1v = (float4*)sW1;
        #pragma unroll
        for (int i = 0; i < 4; ++i) sW1v[tid + 256 * i] = W1v[tid + 256 * i];
        if (tid < 32) sB1[tid] = b1[tid];
        if (tid < 64) sW2[tid] = W2[tid];
        if (tid < 2)  sB2[tid] = b2[tid];
    }
    __syncthreads();

    const int row = blockIdx.x * 256 + tid;
    if (row >= n) return;

    const float4* x0;
    const float4* x1 = nullptr;
    const float4* x2 = nullptr;
    if constexpr (MODE == 0) {
        x0 = (const float4*)(h + (size_t)row * 128);
    } else if constexpr (MODE == 1) {
        int2 p = ((const int2*)ia)[row];
        x0 = (const float4*)(h + (size_t)p.x * 128);
        x1 = (const float4*)(h + (size_t)p.y * 128);
    } else if constexpr (MODE == 2) {
        int c  = ia[row];
        int2 p = ((const int2*)ib)[row];
        x0 = (const float4*)(h + (size_t)c * 128);
        x1 = (const float4*)(h + (size_t)p.x * 128);
        x2 = (const float4*)(h + (size_t)p.y * 128);
    } else {
        int4 q = ((const int4*)ia)[row];
        x0 = (const float4*)(h + (size_t)q.z * 128);
        x1 = (const float4*)(h + (size_t)q.w * 128);
    }

    float acc[32];
    #pragma unroll
    for (int j = 0; j < 32; ++j) acc[j] = sB1[j];

    #pragma unroll 2
    for (int kk = 0; kk < 32; ++kk) {
        float4 a = x0[kk];
        if constexpr (MODE == 1 || MODE == 3) {
            float4 bq = x1[kk];
            a.x += bq.x; a.y += bq.y; a.z += bq.z; a.w += bq.w;
        } else if constexpr (MODE == 2) {
            float4 bq = x1[kk];
            float4 cq = x2[kk];
            a.x += bq.x + cq.x; a.y += bq.y + cq.y;
            a.z += bq.z + cq.z; a.w += bq.w + cq.w;
        }
        const float* wr = &sW1[kk * 4 * 32];
        #pragma unroll
        for (int j = 0; j < 32; ++j) acc[j] = fmaf(a.x, wr[j], acc[j]);
        #pragma unroll
        for (int j = 0; j < 32; ++j) acc[j] = fmaf(a.y, wr[32 + j], acc[j]);
        #pragma unroll
        for (int j = 0; j < 32; ++j) acc[j] = fmaf(a.z, wr[64 + j], acc[j]);
        #pragma unroll
        for (int j = 0; j < 32; ++j) acc[j] = fmaf(a.w, wr[96 + j], acc[j]);
    }

    float o0 = sB2[0], o1 = sB2[1];
    #pragma unroll
    for (int j = 0; j < 32; ++j) {
        float t = fast_tanh(acc[j]);
        o0 = fmaf(t, sW2[2 * j], o0);
        o1 = fmaf(t, sW2[2 * j + 1], o1);
    }
    o0p[row] = fabsf(o0);
    o1p[row] = fabsf(o1);
}

__global__ __launch_bounds__(256)
void pair_k(const float* __restrict__ kat, const float* __restrict__ eat,
            const int* __restrict__ idx,
            float* __restrict__ sig, float* __restrict__ eps, int n)
{
    int i = blockIdx.x * 256 + threadIdx.x;
    if (i >= n) return;
    int2 p = ((const int2*)idx)[i];
    float ka = kat[p.x], kb = kat[p.y];
    float ea = eat[p.x], eb = eat[p.y];
    sig[i] = 0.5f * (ka + kb);
    eps[i] = sqrtf(ea * eb);
}

extern "C" void kernel_launch(void* const* d_in, const int* in_sizes, int n_in,
                              void* d_out, int out_size, void* d_ws, size_t ws_size,
                              hipStream_t stream)
{
    const float* h     = (const float*)d_in[0];
    const int*   bond  = (const int*)d_in[1];
    const int*   ang_c = (const int*)d_in[2];
    const int*   ang_s = (const int*)d_in[3];
    const int*   tor   = (const int*)d_in[4];
    const int*   i14   = (const int*)d_in[5];
    const int*   inb   = (const int*)d_in[6];
    const float* W1a   = (const float*)d_in[7];
    const float* b1a   = (const float*)d_in[8];
    const float* W2a   = (const float*)d_in[9];
    const float* b2a   = (const float*)d_in[10];
    const float* W1b   = (const float*)d_in[11];
    const float* b1b   = (const float*)d_in[12];
    const float* W2b   = (const float*)d_in[13];
    const float* b2b   = (const float*)d_in[14];
    float* out = (float*)d_out;

    dim3 B(256);

    if (ws_size >= WS_NEED) {
        ushort* fragS = (ushort*)d_ws;
        const bf16x8* fragV = (const bf16x8*)d_ws;
        ushort* zb = (ushort*)((char*)d_ws + FRAG_BYTES);
        float2* ke = (float2*)((char*)d_ws + KE_OFF);

        build_frags_k<<<4, B, 0, stream>>>(W1a, W1b, fragS);

        atom_mfma_k<<<(NTILE + 3) / 4, B, 0, stream>>>(
            h, fragV, b1a, W2a, b2a,
            out + OFF_KATOM, out + OFF_EQATOM, zb, ke);

        tail_k<<<NB_TAIL, B, 0, stream>>>(
            zb, ke, bond, ang_c, ang_s, tor, i14, inb,
            b1b, W2b, b2b, out);
    } else {
        mlp_k<0><<<(NATOM    + 255) / 256, B, 0, stream>>>(h, nullptr, nullptr, W1a, b1a, W2a, b2a,
                                                           out + OFF_KATOM, out + OFF_EQATOM, NATOM);
        mlp_k<1><<<(NBOND    + 255) / 256, B, 0, stream>>>(h, bond, nullptr, W1b, b1b, W2b, b2b,
                                                           out + OFF_BOND0, out + OFF_BOND1, NBOND);
        mlp_k<2><<<(NANGLE   + 255) / 256, B, 0, stream>>>(h, ang_c, ang_s, W1b, b1b, W2b, b2b,
                                                           out + OFF_ANG0, out + OFF_ANG1, NANGLE);
        mlp_k<3><<<(NTORSION + 255) / 256, B, 0, stream>>>(h, tor, nullptr, W1b, b1b, W2b, b2b,
                                                           out + OFF_TOR0, out + OFF_TOR1, NTORSION);
        pair_k<<<(N14 + 255) / 256, B, 0, stream>>>(out + OFF_KATOM, out + OFF_EQATOM, i14,
                                                    out + OFF_S14, out + OFF_E14, N14);
        pair_k<<<(NNB + 255) / 256, B, 0, stream>>>(out + OFF_KATOM, out + OFF_EQATOM, inb,
                                                    out + OFF_SNB, out + OFF_ENB, NNB);
    }
}

// Round 10
// 142.904 us; speedup vs baseline: 1.0834x; 1.0556x over previous
//
#include <hip/hip_runtime.h>
#include <math.h>

#define NATOM 300000
#define NBOND 310000
#define NANGLE 550000
#define NTORSION 800000
#define N14 800000
#define NNB 3000000
#define NTILE 18750   // NATOM/16

// output segment offsets (concat order from reference)
#define OFF_KATOM   0
#define OFF_EQATOM  300000
#define OFF_BOND0   600000
#define OFF_BOND1   910000
#define OFF_ANG0    1220000
#define OFF_ANG1    1770000
#define OFF_TOR0    2320000
#define OFF_TOR1    3120000
#define OFF_S14     3920000
#define OFF_E14     4720000
#define OFF_SNB     5520000
#define OFF_ENB     8520000

// tail kernel block ranges (r6 sequential layout — interleave regressed, r8)
#define NB_TOR   3125   // 800000/256 exact
#define NB_ANG   2149   // ceil(550000/256)
#define NB_BOND  1211   // ceil(310000/256)
#define NB_14    1563   // ceil(400000/256), 2 pairs/thread
#define NB_NB    5860   // ceil(1500000/256), 2 pairs/thread
#define NB_TAIL  (NB_TOR + NB_ANG + NB_BOND + NB_14 + NB_NB)

// workspace: [frag table 16KB][zb bf16 19.2MB][ke float2 2.4MB]
#define FRAG_BYTES  16384
#define ZB_BYTES    ((size_t)NATOM * 32 * 2)
#define KE_OFF      (FRAG_BYTES + ZB_BYTES)
#define WS_NEED     (KE_OFF + (size_t)NATOM * 8)

typedef short bf16x8 __attribute__((ext_vector_type(8)));
typedef float f32x4  __attribute__((ext_vector_type(4)));
typedef int   i32x2v __attribute__((ext_vector_type(2)));
typedef int   i32x4v __attribute__((ext_vector_type(4)));

// nontemporal hints: used ONLY in the tail kernel (r9 measured win there;
// NT on the atom kernel's streaming h loads measurably regressed, r9).
#if __has_builtin(__builtin_nontemporal_load)
#define NT_LOAD(p)     __builtin_nontemporal_load(p)
#else
#define NT_LOAD(p)     (*(p))
#endif
#if __has_builtin(__builtin_nontemporal_store)
#define NT_STORE(v, p) __builtin_nontemporal_store((v), (p))
#else
#define NT_STORE(v, p) (*(p) = (v))
#endif

__device__ __forceinline__ float fast_tanh(float z) {
    float az = fabsf(z);
    float e  = __expf(-2.0f * az);
    float t  = __fdividef(1.0f - e, 1.0f + e);
    return copysignf(t, z);
}

__device__ __forceinline__ unsigned short f2bf(float f) {
    unsigned int u = __float_as_uint(f);
    u = u + 0x7fffu + ((u >> 16) & 1u);   // RTNE
    return (unsigned short)(u >> 16);
}

// ---------------- fast path ----------------

// Pre-pack B fragments of W1a/W1b for mfma_f32_16x16x32_bf16 (r3 verbatim).
__global__ __launch_bounds__(256)
void build_frags_k(const float* __restrict__ W1a, const float* __restrict__ W1b,
                   ushort* __restrict__ frag)
{
    int s = blockIdx.x * 256 + threadIdx.x;   // 1024 slots
    if (s >= 1024) return;
    int lane = s & 63;
    int f    = s >> 6;
    int cb   = f & 1;
    int t    = (f >> 1) & 3;
    int mat  = f >> 3;
    const float* W = mat ? W1b : W1a;
    int k0  = t * 32 + (lane >> 4) * 8;
    int col = cb * 16 + (lane & 15);
    ushort* dst = frag + (size_t)s * 8;
    #pragma unroll
    for (int i = 0; i < 8; ++i)
        dst[i] = f2bf(W[(size_t)(k0 + i) * 32 + col]);
}

// r3/r6 verbatim: one 16-row tile per wave, 4 waves/block, direct z stores,
// normal cached h loads (NT here regressed — r9).
__global__ __launch_bounds__(256)
void atom_mfma_k(const float* __restrict__ h, const bf16x8* __restrict__ frag,
                 const float* __restrict__ b1a, const float* __restrict__ W2a,
                 const float* __restrict__ b2a,
                 float* __restrict__ kout, float* __restrict__ eout,
                 ushort* __restrict__ zb, float2* __restrict__ ke)
{
    const int wid  = threadIdx.x >> 6;
    const int lane = threadIdx.x & 63;
    const int tile = blockIdx.x * 4 + wid;
    if (tile >= NTILE) return;
    const int rowbase = tile * 16;
    const int m = lane & 15;
    const int g = lane >> 4;

    const float* ap = h + (size_t)(rowbase + m) * 128 + g * 8;
    bf16x8 afr[4];
    #pragma unroll
    for (int t = 0; t < 4; ++t) {
        float4 x0 = *(const float4*)(ap + t * 32);
        float4 x1 = *(const float4*)(ap + t * 32 + 4);
        bf16x8 a;
        a[0] = (short)f2bf(x0.x); a[1] = (short)f2bf(x0.y);
        a[2] = (short)f2bf(x0.z); a[3] = (short)f2bf(x0.w);
        a[4] = (short)f2bf(x1.x); a[5] = (short)f2bf(x1.y);
        a[6] = (short)f2bf(x1.z); a[7] = (short)f2bf(x1.w);
        afr[t] = a;
    }

    f32x4 acc[2][2];
    #pragma unroll
    for (int mat = 0; mat < 2; ++mat) {
        #pragma unroll
        for (int cb = 0; cb < 2; ++cb) {
            f32x4 c = {0.f, 0.f, 0.f, 0.f};
            #pragma unroll
            for (int t = 0; t < 4; ++t) {
                bf16x8 b = frag[(size_t)((((mat << 2) | t) << 1) | cb) * 64 + lane];
                c = __builtin_amdgcn_mfma_f32_16x16x32_bf16(afr[t], b, c, 0, 0, 0);
            }
            acc[mat][cb] = c;
        }
    }

    // z output (mat=1), bf16, direct scattered stores
    #pragma unroll
    for (int cb = 0; cb < 2; ++cb) {
        int col = cb * 16 + m;
        #pragma unroll
        for (int r = 0; r < 4; ++r) {
            int row = rowbase + g * 4 + r;
            zb[(size_t)row * 32 + col] = f2bf(acc[1][cb][r]);
        }
    }

    // atom MLP epilogue (mat=0)
    const int c0 = m, c1 = 16 + m;
    const float w200 = W2a[2 * c0], w201 = W2a[2 * c0 + 1];
    const float w210 = W2a[2 * c1], w211 = W2a[2 * c1 + 1];
    const float bb0 = b1a[c0], bb1 = b1a[c1];
    float o0[4], o1[4];
    #pragma unroll
    for (int r = 0; r < 4; ++r) {
        float t0 = fast_tanh(acc[0][0][r] + bb0);
        float t1 = fast_tanh(acc[0][1][r] + bb1);
        o0[r] = fmaf(t0, w200, t1 * w210);
        o1[r] = fmaf(t0, w201, t1 * w211);
    }
    #pragma unroll
    for (int mask = 1; mask < 16; mask <<= 1) {
        #pragma unroll
        for (int r = 0; r < 4; ++r) {
            o0[r] += __shfl_xor(o0[r], mask, 64);
            o1[r] += __shfl_xor(o1[r], mask, 64);
        }
    }
    if (m == 0) {
        const float B0 = b2a[0], B1 = b2a[1];
        #pragma unroll
        for (int r = 0; r < 4; ++r) {
            int row = rowbase + g * 4 + r;
            float kv = fabsf(o0[r] + B0);
            float ev = fabsf(o1[r] + B1);
            kout[row] = kv;
            eout[row] = ev;
            ke[row]   = make_float2(kv, ev);
        }
    }
}

__device__ __forceinline__ void add_row_bf(float* acc, const uint4* p) {
    #pragma unroll
    for (int c = 0; c < 4; ++c) {
        uint4 u = p[c];
        unsigned int w[4] = {u.x, u.y, u.z, u.w};
        #pragma unroll
        for (int q = 0; q < 4; ++q) {
            acc[c * 8 + q * 2]     += __uint_as_float(w[q] << 16);
            acc[c * 8 + q * 2 + 1] += __uint_as_float(w[q] & 0xffff0000u);
        }
    }
}

// r6 full-row edge body; index loads nontemporal, output stores nontemporal,
// zb gathers normal (cached — they are the reuse candidates). [r9 tail win]
template<int MODE>
__device__ __forceinline__ void edge_body(const ushort* __restrict__ zb,
                                          const int* __restrict__ ia,
                                          const int* __restrict__ ib,
                                          const float* __restrict__ b1,
                                          const float* __restrict__ W2,
                                          const float* __restrict__ b2,
                                          float* __restrict__ o0p,
                                          float* __restrict__ o1p, int row)
{
    const uint4* p0;
    const uint4* p1;
    const uint4* p2 = nullptr;
    if constexpr (MODE == 1) {
        i32x2v p = NT_LOAD((const i32x2v*)&((const int2*)ia)[row]);
        p0 = (const uint4*)(zb + (size_t)p.x * 32);
        p1 = (const uint4*)(zb + (size_t)p.y * 32);
    } else if constexpr (MODE == 2) {
        int c = NT_LOAD(&ia[row]);
        i32x2v s = NT_LOAD((const i32x2v*)&((const int2*)ib)[row]);
        p0 = (const uint4*)(zb + (size_t)c   * 32);
        p1 = (const uint4*)(zb + (size_t)s.x * 32);
        p2 = (const uint4*)(zb + (size_t)s.y * 32);
    } else {
        i32x4v q = NT_LOAD((const i32x4v*)&((const int4*)ia)[row]);
        p0 = (const uint4*)(zb + (size_t)q.z * 32);
        p1 = (const uint4*)(zb + (size_t)q.w * 32);
    }

    float acc[32];
    #pragma unroll
    for (int j = 0; j < 32; ++j) acc[j] = b1[j];
    add_row_bf(acc, p0);
    add_row_bf(acc, p1);
    if constexpr (MODE == 2) add_row_bf(acc, p2);

    float o0 = b2[0], o1 = b2[1];
    #pragma unroll
    for (int j = 0; j < 32; ++j) {
        float t = fast_tanh(acc[j]);
        o0 = fmaf(t, W2[2 * j],     o0);
        o1 = fmaf(t, W2[2 * j + 1], o1);
    }
    NT_STORE(fabsf(o0), &o0p[row]);
    NT_STORE(fabsf(o1), &o1p[row]);
}

__device__ __forceinline__ void pair_body(const float2* __restrict__ ke,
                                          const int* __restrict__ idx,
                                          float* __restrict__ sig,
                                          float* __restrict__ eps,
                                          int i, int npair)
{
    if (i >= npair) return;
    i32x4v q = NT_LOAD((const i32x4v*)&((const int4*)idx)[i >> 1]);
    float2 a0 = ke[q.x], b0 = ke[q.y];
    float2 a1 = ke[q.z], b1v = ke[q.w];
    NT_STORE(0.5f * (a0.x + b0.x),  &sig[i]);
    NT_STORE(sqrtf(a0.y * b0.y),    &eps[i]);
    NT_STORE(0.5f * (a1.x + b1v.x), &sig[i + 1]);
    NT_STORE(sqrtf(a1.y * b1v.y),   &eps[i + 1]);
}

// All edge MLPs + both pair readouts in ONE dispatch (r6 sequential routing).
__global__ __launch_bounds__(256)
void tail_k(const ushort* __restrict__ zb, const float2* __restrict__ ke,
            const int* __restrict__ bond, const int* __restrict__ angc,
            const int* __restrict__ angs, const int* __restrict__ tor,
            const int* __restrict__ i14, const int* __restrict__ inb,
            const float* __restrict__ b1, const float* __restrict__ W2,
            const float* __restrict__ b2, float* __restrict__ out)
{
    int bid = blockIdx.x;
    int tid = threadIdx.x;
    if (bid < NB_TOR) {
        int row = bid * 256 + tid;
        if (row < NTORSION)
            edge_body<3>(zb, tor, nullptr, b1, W2, b2,
                         out + OFF_TOR0, out + OFF_TOR1, row);
    } else if (bid < NB_TOR + NB_ANG) {
        int row = (bid - NB_TOR) * 256 + tid;
        if (row < NANGLE)
            edge_body<2>(zb, angc, angs, b1, W2, b2,
                         out + OFF_ANG0, out + OFF_ANG1, row);
    } else if (bid < NB_TOR + NB_ANG + NB_BOND) {
        int row = (bid - NB_TOR - NB_ANG) * 256 + tid;
        if (row < NBOND)
            edge_body<1>(zb, bond, nullptr, b1, W2, b2,
                         out + OFF_BOND0, out + OFF_BOND1, row);
    } else if (bid < NB_TOR + NB_ANG + NB_BOND + NB_14) {
        int i = ((bid - NB_TOR - NB_ANG - NB_BOND) * 256 + tid) * 2;
        pair_body(ke, i14, out + OFF_S14, out + OFF_E14, i, N14);
    } else {
        int i = ((bid - NB_TOR - NB_ANG - NB_BOND - NB_14) * 256 + tid) * 2;
        pair_body(ke, inb, out + OFF_SNB, out + OFF_ENB, i, NNB);
    }
}

// ---------------- fallback path (v1, known-good) ----------------

template<int MODE>
__global__ __launch_bounds__(256)
void mlp_k(const float* __restrict__ h,
           const int* __restrict__ ia, const int* __restrict__ ib,
           const float* __restrict__ W1, const float* __restrict__ b1,
           const float* __restrict__ W2, const float* __restrict__ b2,
           float* __restrict__ o0p, float* __restrict__ o1p, int n)
{
    __shared__ float sW1[128 * 32];
    __shared__ float sB1[32];
    __shared__ float sW2[64];
    __shared__ float sB2[2];

    const int tid = threadIdx.x;
    {
        const float4* W1v = (const float4*)W1;
        float4* sW1v = (float4*)sW1;
        #pragma unroll
        for (int i = 0; i < 4; ++i) sW1v[tid + 256 * i] = W1v[tid + 256 * i];
        if (tid < 32) sB1[tid] = b1[tid];
        if (tid < 64) sW2[tid] = W2[tid];
        if (tid < 2)  sB2[tid] = b2[tid];
    }
    __syncthreads();

    const int row = blockIdx.x * 256 + tid;
    if (row >= n) return;

    const float4* x0;
    const float4* x1 = nullptr;
    const float4* x2 = nullptr;
    if constexpr (MODE == 0) {
        x0 = (const float4*)(h + (size_t)row * 128);
    } else if constexpr (MODE == 1) {
        int2 p = ((const int2*)ia)[row];
        x0 = (const float4*)(h + (size_t)p.x * 128);
        x1 = (const float4*)(h + (size_t)p.y * 128);
    } else if constexpr (MODE == 2) {
        int c  = ia[row];
        int2 p = ((const int2*)ib)[row];
        x0 = (const float4*)(h + (size_t)c * 128);
        x1 = (const float4*)(h + (size_t)p.x * 128);
        x2 = (const float4*)(h + (size_t)p.y * 128);
    } else {
        int4 q = ((const int4*)ia)[row];
        x0 = (const float4*)(h + (size_t)q.z * 128);
        x1 = (const float4*)(h + (size_t)q.w * 128);
    }

    float acc[32];
    #pragma unroll
    for (int j = 0; j < 32; ++j) acc[j] = sB1[j];

    #pragma unroll 2
    for (int kk = 0; kk < 32; ++kk) {
        float4 a = x0[kk];
        if constexpr (MODE == 1 || MODE == 3) {
            float4 bq = x1[kk];
            a.x += bq.x; a.y += bq.y; a.z += bq.z; a.w += bq.w;
        } else if constexpr (MODE == 2) {
            float4 bq = x1[kk];
            float4 cq = x2[kk];
            a.x += bq.x + cq.x; a.y += bq.y + cq.y;
            a.z += bq.z + cq.z; a.w += bq.w + cq.w;
        }
        const float* wr = &sW1[kk * 4 * 32];
        #pragma unroll
        for (int j = 0; j < 32; ++j) acc[j] = fmaf(a.x, wr[j], acc[j]);
        #pragma unroll
        for (int j = 0; j < 32; ++j) acc[j] = fmaf(a.y, wr[32 + j], acc[j]);
        #pragma unroll
        for (int j = 0; j < 32; ++j) acc[j] = fmaf(a.z, wr[64 + j], acc[j]);
        #pragma unroll
        for (int j = 0; j < 32; ++j) acc[j] = fmaf(a.w, wr[96 + j], acc[j]);
    }

    float o0 = sB2[0], o1 = sB2[1];
    #pragma unroll
    for (int j = 0; j < 32; ++j) {
        float t = fast_tanh(acc[j]);
        o0 = fmaf(t, sW2[2 * j], o0);
        o1 = fmaf(t, sW2[2 * j + 1], o1);
    }
    o0p[row] = fabsf(o0);
    o1p[row] = fabsf(o1);
}

__global__ __launch_bounds__(256)
void pair_k(const float* __restrict__ kat, const float* __restrict__ eat,
            const int* __restrict__ idx,
            float* __restrict__ sig, float* __restrict__ eps, int n)
{
    int i = blockIdx.x * 256 + threadIdx.x;
    if (i >= n) return;
    int2 p = ((const int2*)idx)[i];
    float ka = kat[p.x], kb = kat[p.y];
    float ea = eat[p.x], eb = eat[p.y];
    sig[i] = 0.5f * (ka + kb);
    eps[i] = sqrtf(ea * eb);
}

extern "C" void kernel_launch(void* const* d_in, const int* in_sizes, int n_in,
                              void* d_out, int out_size, void* d_ws, size_t ws_size,
                              hipStream_t stream)
{
    const float* h     = (const float*)d_in[0];
    const int*   bond  = (const int*)d_in[1];
    const int*   ang_c = (const int*)d_in[2];
    const int*   ang_s = (const int*)d_in[3];
    const int*   tor   = (const int*)d_in[4];
    const int*   i14   = (const int*)d_in[5];
    const int*   inb   = (const int*)d_in[6];
    const float* W1a   = (const float*)d_in[7];
    const float* b1a   = (const float*)d_in[8];
    const float* W2a   = (const float*)d_in[9];
    const float* b2a   = (const float*)d_in[10];
    const float* W1b   = (const float*)d_in[11];
    const float* b1b   = (const float*)d_in[12];
    const float* W2b   = (const float*)d_in[13];
    const float* b2b   = (const float*)d_in[14];
    float* out = (float*)d_out;

    dim3 B(256);

    if (ws_size >= WS_NEED) {
        ushort* fragS = (ushort*)d_ws;
        const bf16x8* fragV = (const bf16x8*)d_ws;
        ushort* zb = (ushort*)((char*)d_ws + FRAG_BYTES);
        float2* ke = (float2*)((char*)d_ws + KE_OFF);

        build_frags_k<<<4, B, 0, stream>>>(W1a, W1b, fragS);

        atom_mfma_k<<<(NTILE + 3) / 4, B, 0, stream>>>(
            h, fragV, b1a, W2a, b2a,
            out + OFF_KATOM, out + OFF_EQATOM, zb, ke);

        tail_k<<<NB_TAIL, B, 0, stream>>>(
            zb, ke, bond, ang_c, ang_s, tor, i14, inb,
            b1b, W2b, b2b, out);
    } else {
        mlp_k<0><<<(NATOM    + 255) / 256, B, 0, stream>>>(h, nullptr, nullptr, W1a, b1a, W2a, b2a,
                                                           out + OFF_KATOM, out + OFF_EQATOM, NATOM);
        mlp_k<1><<<(NBOND    + 255) / 256, B, 0, stream>>>(h, bond, nullptr, W1b, b1b, W2b, b2b,
                                                           out + OFF_BOND0, out + OFF_BOND1, NBOND);
        mlp_k<2><<<(NANGLE   + 255) / 256, B, 0, stream>>>(h, ang_c, ang_s, W1b, b1b, W2b, b2b,
                                                           out + OFF_ANG0, out + OFF_ANG1, NANGLE);
        mlp_k<3><<<(NTORSION + 255) / 256, B, 0, stream>>>(h, tor, nullptr, W1b, b1b, W2b, b2b,
                                                           out + OFF_TOR0, out + OFF_TOR1, NTORSION);
        pair_k<<<(N14 + 255) / 256, B, 0, stream>>>(out + OFF_KATOM, out + OFF_EQATOM, i14,
                                                    out + OFF_S14, out + OFF_E14, N14);
        pair_k<<<(NNB + 255) / 256, B, 0, stream>>>(out + OFF_KATOM, out + OFF_EQATOM, inb,
                                                    out + OFF_SNB, out + OFF_ENB, NNB);
    }
}